// Round 1
// baseline (1916.923 us; speedup 1.0000x reference)
//
#include <hip/hip_runtime.h>
#include <hip/hip_bf16.h>

#define NNODES 50000
#define D 300
#define NF4 75   // D/4 float4 per row

// ---------------- CSR build ----------------

__global__ void hist_kernel(const int* __restrict__ dst, int* __restrict__ cnt, int E) {
    int e = blockIdx.x * blockDim.x + threadIdx.x;
    if (e < E) atomicAdd(&cnt[dst[e]], 1);
}

__global__ __launch_bounds__(1024) void scan_kernel(const int* __restrict__ cnt,
                                                    int* __restrict__ row_start,
                                                    int* __restrict__ cursor, int n) {
    __shared__ int sd[1024];
    __shared__ int s_off;
    int tid = threadIdx.x;
    if (tid == 0) s_off = 0;
    __syncthreads();
    for (int base = 0; base < n; base += 1024) {
        int i = base + tid;
        int v = (i < n) ? cnt[i] : 0;
        sd[tid] = v;
        __syncthreads();
        // Hillis-Steele inclusive scan
        for (int s = 1; s < 1024; s <<= 1) {
            int t = (tid >= s) ? sd[tid - s] : 0;
            __syncthreads();
            sd[tid] += t;
            __syncthreads();
        }
        int off = s_off;
        if (i < n) {
            int excl = sd[tid] - v;
            row_start[i] = off + excl;
            cursor[i]    = off + excl;
        }
        int total = sd[1023];
        __syncthreads();
        if (tid == 0) s_off = off + total;
        __syncthreads();
    }
    if (tid == 0) row_start[n] = s_off;
}

__global__ void scatter_kernel(const int* __restrict__ src, const int* __restrict__ dst,
                               int* __restrict__ cursor, int* __restrict__ csr_src, int E) {
    int e = blockIdx.x * blockDim.x + threadIdx.x;
    if (e < E) {
        int pos = atomicAdd(&cursor[dst[e]], 1);
        csr_src[pos] = src[e];
    }
}

// ---------------- aggregation: one wave per node ----------------

__global__ __launch_bounds__(256) void agg_kernel(const float4* __restrict__ feat,
                                                  const int* __restrict__ row_start,
                                                  const int* __restrict__ csr_src,
                                                  float4* __restrict__ out, int n) {
    int gwave = blockIdx.x * 4 + (threadIdx.x >> 6);
    int lane  = threadIdx.x & 63;
    if (gwave >= n) return;
    int beg = row_start[gwave];
    int end = row_start[gwave + 1];
    float4 a0 = {0.f, 0.f, 0.f, 0.f};
    float4 a1 = {0.f, 0.f, 0.f, 0.f};
    for (int i = beg; i < end; ++i) {
        int s = csr_src[i];
        const float4* r = feat + (size_t)s * NF4;
        float4 v = r[lane];
        a0.x += v.x; a0.y += v.y; a0.z += v.z; a0.w += v.w;
        if (lane < NF4 - 64) {
            float4 u = r[64 + lane];
            a1.x += u.x; a1.y += u.y; a1.z += u.z; a1.w += u.w;
        }
    }
    float4* o = out + (size_t)gwave * NF4;
    o[lane] = a0;
    if (lane < NF4 - 64) o[64 + lane] = a1;
}

// ---------------- GEMM + bias + activation ----------------
// out[n,c] = sum_k A[n,k] * W[k,c] + b[c], then relu (ACT=0) or sigmoid (ACT=1)

#define BM 128
#define BN 64
#define BK 20
#define APAD 132

template <int ACT>
__global__ __launch_bounds__(256) void gemm_act(const float* __restrict__ A,
                                                const float* __restrict__ W,
                                                const float* __restrict__ bias,
                                                float* __restrict__ out, int M) {
    __shared__ __align__(16) float As[BK][APAD];  // [k][m]
    __shared__ __align__(16) float Ws[BK][BN];    // [k][c]
    int tid = threadIdx.x;
    int tx = tid & 15;   // col group: cols tx*4 .. tx*4+3
    int ty = tid >> 4;   // row group: rows ty*8 .. ty*8+7
    int row0 = blockIdx.y * BM;
    int col0 = blockIdx.x * BN;

    float acc[8][4];
#pragma unroll
    for (int i = 0; i < 8; i++)
#pragma unroll
        for (int j = 0; j < 4; j++) acc[i][j] = 0.f;

    for (int k0 = 0; k0 < D; k0 += BK) {
        // stage A tile: BM*BK = 2560 elems, 10 per thread
#pragma unroll
        for (int i = 0; i < 10; i++) {
            int idx = tid + i * 256;
            int m = idx / BK, k = idx % BK;
            int row = row0 + m;
            As[k][m] = (row < M) ? A[(size_t)row * D + k0 + k] : 0.f;
        }
        // stage W tile: BK*BN = 1280 elems, 5 per thread
#pragma unroll
        for (int i = 0; i < 5; i++) {
            int idx = tid + i * 256;
            int k = idx / BN, c = idx % BN;
            int col = col0 + c;
            Ws[k][c] = (col < D) ? W[(size_t)(k0 + k) * D + col] : 0.f;
        }
        __syncthreads();
#pragma unroll
        for (int k = 0; k < BK; k++) {
            float4 a0 = *(const float4*)&As[k][ty * 8];
            float4 a1 = *(const float4*)&As[k][ty * 8 + 4];
            float4 wv = *(const float4*)&Ws[k][tx * 4];
            float av[8] = {a0.x, a0.y, a0.z, a0.w, a1.x, a1.y, a1.z, a1.w};
            float wl[4] = {wv.x, wv.y, wv.z, wv.w};
#pragma unroll
            for (int i = 0; i < 8; i++)
#pragma unroll
                for (int j = 0; j < 4; j++) acc[i][j] += av[i] * wl[j];
        }
        __syncthreads();
    }
    // epilogue
#pragma unroll
    for (int i = 0; i < 8; i++) {
        int row = row0 + ty * 8 + i;
        if (row >= M) continue;
#pragma unroll
        for (int j = 0; j < 4; j++) {
            int col = col0 + tx * 4 + j;
            if (col >= D) continue;
            float v = acc[i][j] + bias[col];
            if (ACT == 0) v = fmaxf(v, 0.f);
            else          v = 1.f / (1.f + __expf(-v));
            out[(size_t)row * D + col] = v;
        }
    }
}

// ---------------- launch ----------------

extern "C" void kernel_launch(void* const* d_in, const int* in_sizes, int n_in,
                              void* d_out, int out_size, void* d_ws, size_t ws_size,
                              hipStream_t stream) {
    const float* feat = (const float*)d_in[0];
    const int*   src  = (const int*)d_in[1];
    const int*   dst  = (const int*)d_in[2];
    const float* W1   = (const float*)d_in[3];
    const float* b1   = (const float*)d_in[4];
    const float* W2   = (const float*)d_in[5];
    const float* b2   = (const float*)d_in[6];
    const float* W3   = (const float*)d_in[7];
    const float* b3   = (const float*)d_in[8];
    float* outp = (float*)d_out;

    int N = in_sizes[0] / D;   // 50000
    int E = in_sizes[1];       // 1600000

    char* w = (char*)d_ws;
    // offsets (16B aligned)
    int* cnt       = (int*)(w + 0);                       // N ints
    int* row_start = (int*)(w + 200192);                  // N+1 ints
    int* cursor    = (int*)(w + 400384);                  // N ints
    int* csr_src   = (int*)(w + 600576);                  // E ints
    float* agg     = (float*)(w + 7000576);               // N*D floats (60 MB)
    float* h       = outp;                                // reuse d_out as inter-layer buffer

    hipMemsetAsync(cnt, 0, (size_t)N * sizeof(int), stream);
    hist_kernel<<<(E + 255) / 256, 256, 0, stream>>>(dst, cnt, E);
    scan_kernel<<<1, 1024, 0, stream>>>(cnt, row_start, cursor, N);
    scatter_kernel<<<(E + 255) / 256, 256, 0, stream>>>(src, dst, cursor, csr_src, E);

    dim3 ggrid((D + BN - 1) / BN, (N + BM - 1) / BM);  // (5, 391)
    int agrid = (N * 64 + 255) / 256;                  // one wave per node

    // layer 1
    agg_kernel<<<agrid, 256, 0, stream>>>((const float4*)feat, row_start, csr_src,
                                          (float4*)agg, N);
    gemm_act<0><<<ggrid, 256, 0, stream>>>(agg, W1, b1, h, N);
    // layer 2
    agg_kernel<<<agrid, 256, 0, stream>>>((const float4*)h, row_start, csr_src,
                                          (float4*)agg, N);
    gemm_act<0><<<ggrid, 256, 0, stream>>>(agg, W2, b2, h, N);
    // layer 3
    agg_kernel<<<agrid, 256, 0, stream>>>((const float4*)h, row_start, csr_src,
                                          (float4*)agg, N);
    gemm_act<1><<<ggrid, 256, 0, stream>>>(agg, W3, b3, outp, N);
}